// Round 9
// baseline (394.736 us; speedup 1.0000x reference)
//
#include <hip/hip_runtime.h>
#include <math.h>

// B=32, M=1024, D=768, H=256.
// Vb = bf16(V); g = mean_m V (fused with cast); gW = g@WVw^T (fp32)
// [Vp | resv] = Vb @ [WVw;resw]^T (+epilogues), bf16      -- MFMA dbuf-core, XCD-swizzled
// rn[m] = ||Vp_m||^2 ; shift[b] = max_m rn
// E = exp(Vp@Vp^T - shift[b]) bf16 (symmetric), Z[m] += row-sums (fused atomics)
// k_t12 (fused): t1 = E @ (Vp/Z) -> LDS; t2 = t1 @ Wc; writes t2T directly
// out = relu((E @ t2T^T)/Z[m] + resv)  fp32               -- MFMA dbuf-core

typedef __attribute__((ext_vector_type(8))) short bf16x8;
typedef __attribute__((ext_vector_type(4))) float f32x4;

__device__ __forceinline__ ushort f2b(float f) {
    unsigned u = __float_as_uint(f);
    return (ushort)((u + 0x7fffu + ((u >> 16) & 1u)) >> 16);
}
__device__ __forceinline__ float b2f(ushort u) {
    return __uint_as_float((unsigned)u << 16);
}
__device__ __forceinline__ uint4 pack8(float4 a, float4 b) {
    uint4 r;
    r.x = f2b(a.x) | ((unsigned)f2b(a.y) << 16);
    r.y = f2b(a.z) | ((unsigned)f2b(a.w) << 16);
    r.z = f2b(b.x) | ((unsigned)f2b(b.y) << 16);
    r.w = f2b(b.z) | ((unsigned)f2b(b.w) << 16);
    return r;
}

__device__ __forceinline__ void gl16(const void* g, void* l) {
    __builtin_amdgcn_global_load_lds(
        (__attribute__((address_space(1))) const unsigned*)g,
        (__attribute__((address_space(3))) unsigned*)l, 16, 0, 0);
}

// ---- 128x128 GEMM core, BK=64, global_load_lds(16B), XOR-swizzled LDS,
// ping-pong double-buffer: next tile's loads issued BEFORE current tile's MFMA
// (T3 minimum-2-phase).  K must be a multiple of 128.  LDS: 4 x 16 KB.
__device__ __forceinline__ void gemm_core(const ushort* __restrict__ A,
                                          const ushort* __restrict__ Bt,
                                          int K,
                                          ushort* As0, ushort* Bs0,
                                          ushort* As1, ushort* Bs1,
                                          f32x4 acc[4][4]) {
    const int tid = threadIdx.x;
    const int lane = tid & 63;
    const int wave = tid >> 6;
    const int l8 = lane >> 3, l7 = lane & 7;
    const int swz = ((l7 ^ l8) << 4);                 // inverse-swizzled global source
    const char* pa[4];
    const char* pb[4];
    int lo[4];                                        // wave-uniform LDS chunk offsets
    #pragma unroll
    for (int i = 0; i < 4; ++i) {
        int r = (wave * 4 + i) * 8 + l8;              // staged row 0..127
        pa[i] = (const char*)A + (size_t)r * (K * 2) + swz;
        pb[i] = (const char*)Bt + (size_t)r * (K * 2) + swz;
        lo[i] = (wave * 4 + i) * 512;                 // 1 KB per gl16 chunk
    }
    const int rr = lane & 15;
    const int kq = (lane >> 4) << 4;
    const int mask = (rr & 7) << 4;
    const int c0 = kq ^ mask;
    const int c1 = (64 + kq) ^ mask;
    const int wr = (wave >> 1) * 64, wc = (wave & 1) * 64;
    const int arow0 = (wr + rr) * 128, brow0 = (wc + rr) * 128;

#define STAGE_TO(Abuf, Bbuf) \
    { _Pragma("unroll") for (int i = 0; i < 4; ++i) { \
        gl16(pa[i], (Abuf) + lo[i]); gl16(pb[i], (Bbuf) + lo[i]); \
        pa[i] += 128; pb[i] += 128; } }

#define COMPUTE_ON(Abuf, Bbuf) \
    { _Pragma("unroll") for (int ks = 0; ks < 2; ++ks) { \
        const int cc = ks ? c1 : c0; \
        bf16x8 av[4], bv[4]; \
        _Pragma("unroll") for (int i = 0; i < 4; ++i) { \
            av[i] = *(const bf16x8*)((const char*)(Abuf) + arow0 + i * 2048 + cc); \
            bv[i] = *(const bf16x8*)((const char*)(Bbuf) + brow0 + i * 2048 + cc); } \
        _Pragma("unroll") for (int i = 0; i < 4; ++i) \
            _Pragma("unroll") for (int j = 0; j < 4; ++j) \
                acc[i][j] = __builtin_amdgcn_mfma_f32_16x16x32_bf16(av[i], bv[j], acc[i][j], 0, 0, 0); } }

    STAGE_TO(As0, Bs0);                               // prologue: k-step 0
    __syncthreads();
    for (int k0 = 0; k0 < K; k0 += 128) {
        if (k0 + 64 < K) STAGE_TO(As1, Bs1);          // in flight during compute
        COMPUTE_ON(As0, Bs0);
        __syncthreads();                              // drains vmcnt; buf1 ready
        if (k0 + 128 < K) STAGE_TO(As0, Bs0);
        COMPUTE_ON(As1, Bs1);
        __syncthreads();
    }
#undef STAGE_TO
#undef COMPUTE_ON
}

#define EPI_COORDS \
    const int lane = threadIdx.x & 63; \
    const int wave = threadIdx.x >> 6; \
    const int rb = (wave >> 1) * 64 + (lane >> 4) * 4; \
    const int cb = (wave & 1) * 64 + (lane & 15);

#define GEMM_LDS \
    __shared__ ushort As0[128 * 64], Bs0[128 * 64]; \
    __shared__ ushort As1[128 * 64], Bs1[128 * 64];

// ---- cast V->bf16 fused with column partial sums for the mean (16 row-chunks of 64)
__global__ __launch_bounds__(192) void k_castmean(const float* __restrict__ V,
                                                  ushort* __restrict__ Vb,
                                                  float* __restrict__ gpart) {
    const int b = blockIdx.x, mc = blockIdx.y, t = threadIdx.x;
    const size_t base = ((size_t)(b * 1024 + mc * 64)) * 768 + t * 4;
    const float* src = V + base;
    ushort* dst = Vb + base;
    float4 s = make_float4(0.f, 0.f, 0.f, 0.f);
    for (int r = 0; r < 64; ++r) {
        float4 v = *(const float4*)(src + (size_t)r * 768);
        s.x += v.x; s.y += v.y; s.z += v.z; s.w += v.w;
        unsigned u0 = f2b(v.x) | ((unsigned)f2b(v.y) << 16);
        unsigned u1 = f2b(v.z) | ((unsigned)f2b(v.w) << 16);
        *(uint2*)(dst + (size_t)r * 768) = make_uint2(u0, u1);
    }
    *(float4*)&gpart[(size_t)(mc * 32 + b) * 768 + t * 4] = s;
}

__global__ __launch_bounds__(256) void k_gsum(const float* __restrict__ gpart, float* __restrict__ g) {
    int idx = blockIdx.x * 256 + threadIdx.x;       // < 24576
    float s = 0.f;
    #pragma unroll
    for (int c = 0; c < 16; ++c) s += gpart[(size_t)c * 24576 + idx];
    g[idx] = s * (1.0f / 1024.0f);
}

__global__ __launch_bounds__(256) void k_gW(const float* __restrict__ g,
                                            const float* __restrict__ WVw,
                                            float* __restrict__ gW) {
    int idx = blockIdx.x * 256 + threadIdx.x;       // < 8192
    int b = idx >> 8, h = idx & 255;
    const float* gr = g + b * 768;
    const float* wr = WVw + (size_t)h * 768;
    float s = 0.f;
    for (int d = 0; d < 768; ++d) s += gr[d] * wr[d];
    gW[idx] = s;
}

__global__ __launch_bounds__(256) void k_castw(const float* __restrict__ WVw,
                                               const float* __restrict__ resw,
                                               ushort* __restrict__ Wcat) {
    int id = blockIdx.x * 256 + threadIdx.x;        // < 49152
    int n = id / 96, c = (id - n * 96) * 8;
    const float* src = (n < 256) ? (WVw + (size_t)n * 768 + c) : (resw + (size_t)(n - 256) * 768 + c);
    *(uint4*)(Wcat + (size_t)n * 768 + c) = pack8(*(const float4*)src, *(const float4*)(src + 4));
}

// ---- WcT[k][h] = bf16(Wc[h][k]), 256x256
__global__ __launch_bounds__(256) void k_wct(const float* __restrict__ Wc, ushort* __restrict__ WcT) {
    __shared__ float t[64][65];
    const int r0 = blockIdx.y * 64, c0 = blockIdx.x * 64;
    const int tid = threadIdx.x;
    #pragma unroll
    for (int i = 0; i < 4; ++i) {
        int r = (tid >> 4) + i * 16, c4 = (tid & 15) * 4;
        float4 v = *(const float4*)&Wc[(size_t)(r0 + r) * 256 + c0 + c4];
        t[r][c4] = v.x; t[r][c4 + 1] = v.y; t[r][c4 + 2] = v.z; t[r][c4 + 3] = v.w;
    }
    __syncthreads();
    #pragma unroll
    for (int i = 0; i < 4; ++i) {
        int oc = (tid >> 4) + i * 16, r4 = (tid & 15) * 4;
        unsigned lo = f2b(t[r4][oc]) | ((unsigned)f2b(t[r4 + 1][oc]) << 16);
        unsigned hi = f2b(t[r4 + 2][oc]) | ((unsigned)f2b(t[r4 + 3][oc]) << 16);
        *(uint2*)&WcT[(size_t)(c0 + oc) * 256 + r0 + r4] = make_uint2(lo, hi);
    }
}

// ---- k_proj: [32768 x 512] = Vb @ Wcat^T.  1-D grid 1024, XCD-swizzled.
__global__ __launch_bounds__(256) void k_proj(const ushort* __restrict__ Vb, const ushort* __restrict__ Wcat,
                                              const float* __restrict__ WVb, const float* __restrict__ resb,
                                              const float* __restrict__ gW, const float* __restrict__ alpha_p,
                                              ushort* __restrict__ Vp, ushort* __restrict__ resv) {
    GEMM_LDS
    f32x4 acc[4][4] = {};
    const int j = (blockIdx.x & 7) * 128 + (blockIdx.x >> 3);  // bijective, nwg%8==0
    const int n0 = (j & 3) * 128, m0 = (j >> 2) * 128;
    gemm_core(Vb + (size_t)m0 * 768, Wcat + (size_t)n0 * 768, 768, As0, Bs0, As1, Bs1, acc);
    EPI_COORDS
    const float alpha = *alpha_p, oma = 1.0f - alpha;
    #pragma unroll
    for (int i = 0; i < 4; ++i)
        #pragma unroll
        for (int jj = 0; jj < 4; ++jj) {
            int gcol = n0 + cb + jj * 16;
            #pragma unroll
            for (int r = 0; r < 4; ++r) {
                int grow = m0 + rb + i * 16 + r;
                float v = acc[i][jj][r];
                if (gcol < 256) {
                    float o = alpha * v + oma * gW[((grow >> 10) << 8) + gcol] + WVb[gcol];
                    Vp[(size_t)grow * 256 + gcol] = f2b(o);
                } else {
                    resv[(size_t)grow * 256 + gcol - 256] = f2b(v + resb[gcol - 256]);
                }
            }
        }
}

// ---- k_rownorm: rn[row] = ||Vp_row||^2
__global__ __launch_bounds__(256) void k_rownorm(const ushort* __restrict__ Vp, float* __restrict__ rn) {
    const int row = blockIdx.x * 4 + (threadIdx.x >> 6);
    const int lane = threadIdx.x & 63;
    uint2 v = *(const uint2*)(Vp + (size_t)row * 256 + lane * 4);
    float f0 = b2f((ushort)(v.x & 0xffff)), f1 = b2f((ushort)(v.x >> 16));
    float f2 = b2f((ushort)(v.y & 0xffff)), f3 = b2f((ushort)(v.y >> 16));
    float s = f0 * f0 + f1 * f1 + f2 * f2 + f3 * f3;
    #pragma unroll
    for (int o = 32; o > 0; o >>= 1) s += __shfl_xor(s, o, 64);
    if (lane == 0) rn[row] = s;
}

__global__ __launch_bounds__(256) void k_shift(const float* __restrict__ rn, float* __restrict__ shift) {
    const int b = blockIdx.x, tid = threadIdx.x;
    const float* p = rn + b * 1024;
    float m = fmaxf(fmaxf(p[tid], p[tid + 256]), fmaxf(p[tid + 512], p[tid + 768]));
    #pragma unroll
    for (int o = 32; o > 0; o >>= 1) m = fmaxf(m, __shfl_xor(m, o, 64));
    __shared__ float red[4];
    if ((tid & 63) == 0) red[tid >> 6] = m;
    __syncthreads();
    if (tid == 0)
        shift[b] = fmaxf(fmaxf(red[0], red[1]), fmaxf(red[2], red[3]));
}

// ---- k_sim: E_b = exp(Vp_b @ Vp_b^T - shift[b]) bf16, fused row-sum atomics into Z.
__global__ __launch_bounds__(256) void k_sim(const ushort* __restrict__ Vp,
                                             const float* __restrict__ shift,
                                             ushort* __restrict__ E,
                                             float* __restrict__ Z) {
    GEMM_LDS
    f32x4 acc[4][4] = {};
    const int j = (blockIdx.x & 7) * 256 + (blockIdx.x >> 3);
    const int n0 = (j & 7) * 128, m0 = ((j >> 3) & 7) * 128, b = j >> 6;
    const ushort* Vb_ = Vp + (size_t)b * 1024 * 256;
    gemm_core(Vb_ + (size_t)m0 * 256, Vb_ + (size_t)n0 * 256, 256, As0, Bs0, As1, Bs1, acc);
    ushort* Eb = E + ((size_t)b << 20);
    const float sh = shift[b];
    EPI_COORDS
    #pragma unroll
    for (int i = 0; i < 4; ++i)
        #pragma unroll
        for (int r = 0; r < 4; ++r) {
            const int row = m0 + rb + i * 16 + r;
            float e[4];
            float s = 0.f;
            #pragma unroll
            for (int jj = 0; jj < 4; ++jj) {
                e[jj] = __expf(acc[i][jj][r] - sh);
                s += e[jj];
                Eb[(size_t)row * 1024 + n0 + cb + jj * 16] = f2b(e[jj]);
            }
            s += __shfl_xor(s, 1, 64);
            s += __shfl_xor(s, 2, 64);
            s += __shfl_xor(s, 4, 64);
            s += __shfl_xor(s, 8, 64);
            if ((lane & 15) == 0)
                atomicAdd(&Z[b * 1024 + row], s);
        }
}

// ---- k_trbs: VpZT[b][h][n] = Vp[b][n][h] / Z[b*1024+n]
__global__ __launch_bounds__(256) void k_trbs(const ushort* __restrict__ Vp,
                                              const float* __restrict__ Z,
                                              ushort* __restrict__ VpZT) {
    __shared__ ushort t[64][68];
    const int b = blockIdx.z;
    const ushort* ib = Vp + (size_t)b * 1024 * 256;
    ushort* ob = VpZT + (size_t)b * 256 * 1024;
    const int c0 = blockIdx.x * 64, r0 = blockIdx.y * 64;
    const int tid = threadIdx.x;
    #pragma unroll
    for (int i = 0; i < 4; ++i) {
        int r = (tid >> 4) + i * 16, c4 = (tid & 15) * 4;
        uint2 v = *(const uint2*)(ib + (size_t)(r0 + r) * 256 + c0 + c4);
        float iz = 1.0f / Z[b * 1024 + r0 + r];
        unsigned lo = f2b(b2f((ushort)(v.x & 0xffff)) * iz) |
                      ((unsigned)f2b(b2f((ushort)(v.x >> 16)) * iz) << 16);
        unsigned hi = f2b(b2f((ushort)(v.y & 0xffff)) * iz) |
                      ((unsigned)f2b(b2f((ushort)(v.y >> 16)) * iz) << 16);
        *(uint2*)&t[r][c4] = make_uint2(lo, hi);
    }
    __syncthreads();
    #pragma unroll
    for (int i = 0; i < 4; ++i) {
        int oc = (tid >> 4) + i * 16, r4 = (tid & 15) * 4;
        unsigned lo = t[r4][oc] | ((unsigned)t[r4 + 1][oc] << 16);
        unsigned hi = t[r4 + 2][oc] | ((unsigned)t[r4 + 3][oc] << 16);
        *(uint2*)(ob + (size_t)(c0 + oc) * 1024 + r0 + r4) = make_uint2(lo, hi);
    }
}

// ---- k_t12 (fused): per block: 128 rows m x full 256 cols.
// Phase 1: t1 = E[m-panel] @ VpZT^T (K=1024) -> LDS (XOR-swizzled 128x256 bf16)
// Phase 2: t2 = t1 @ WcT^T (K=256), B-frags direct from L2
// Epilogue: transpose via LDS, write t2T[b][h][m] coalesced.
// 512 threads = 8 waves (2 row x 4 col quadrants).  Grid 256, XCD-swizzled.
__global__ __launch_bounds__(512) void k_t12(const ushort* __restrict__ E,
                                             const ushort* __restrict__ VpZT,
                                             const ushort* __restrict__ WcT,
                                             ushort* __restrict__ t2T) {
    __shared__ char smem[65536];
    char* Asb = smem;            // 16 KB: 128 rows x 128 B  (phase 1)
    char* Bsb = smem + 16384;    // 32 KB: 256 rows x 128 B  (phase 1)
    // whole smem = t1buf [128 m][512 B] (phase 2 A), then tT [256 h][256 B]

    const int j = (blockIdx.x & 7) * 32 + (blockIdx.x >> 3);
    const int m0 = (j & 7) * 128;
    const int b = j >> 3;
    const ushort* Eb = E + ((size_t)b << 20) + (size_t)m0 * 1024;
    const ushort* Vz = VpZT + (size_t)b * 256 * 1024;
    const int tid = threadIdx.x;
    const int lane = tid & 63, wave = tid >> 6;
    const int l8 = lane >> 3, l7 = lane & 7;
    const int swz = (l7 ^ l8) << 4;

    const char* pa[2]; char* la[2];
    const char* pb[4]; char* lb[4];
    #pragma unroll
    for (int ii = 0; ii < 2; ++ii) {
        int r = wave * 16 + ii * 8 + l8;
        pa[ii] = (const char*)(Eb + (size_t)r * 1024) + swz;
        la[ii] = Asb + (wave * 16 + ii * 8) * 128;
    }
    #pragma unroll
    for (int ii = 0; ii < 4; ++ii) {
        int r = wave * 32 + ii * 8 + l8;
        pb[ii] = (const char*)(Vz + (size_t)r * 1024) + swz;
        lb[ii] = Bsb + (wave * 32 + ii * 8) * 128;
    }
    const int rr = lane & 15;
    const int kq = (lane >> 4) << 4;
    const int mask = (rr & 7) << 4;
    const int wr = (wave >> 2) * 64, wc = (wave & 3) * 64;
    f32x4 acc[4][4] = {};
    for (int k0 = 0; k0 < 1024; k0 += 64) {
        __syncthreads();
        #pragma unroll
        for (int ii = 0; ii < 2; ++ii) { gl16(pa[ii], la[ii]); pa[ii] += 128; }
        #pragma unroll
        for (int ii = 0; ii < 4; ++ii) { gl16(pb[ii], lb[ii]); pb[ii] += 128; }
        __syncthreads();
        #pragma unroll
        for (int ks = 0; ks < 2; ++ks) {
            const int cc = (ks * 64 + kq) ^ mask;
            bf16x8 av[4], bv[4];
            #pragma unroll
            for (int i = 0; i < 4; ++i) {
                av[i] = *(const bf16x8*)(Asb + (wr + i * 16 + rr) * 128 + cc);
                bv[i] = *(const bf16x8*)(Bsb + (wc + i * 16 + rr) * 128 + cc);
            }
            #pragma unroll
            for (int i = 0; i < 4; ++i)
                #pragma unroll
                for (int jj = 0; jj < 4; ++jj)
                    acc[i][jj] = __builtin_amdgcn_mfma_f32_16x16x32_bf16(av[i], bv[jj], acc[i][jj], 0, 0, 0);
        }
    }
    // epilogue 1: t1 -> smem [128 m][256 h] bf16, byte = m*512 + ((2h) ^ ((m&7)<<4))
    __syncthreads();
    const int rb = wr + (lane >> 4) * 4;
    const int cbh = wc + (lane & 15);
    #pragma unroll
    for (int i = 0; i < 4; ++i)
        #pragma unroll
        for (int jj = 0; jj < 4; ++jj) {
            int h = cbh + jj * 16;
            #pragma unroll
            for (int r = 0; r < 4; ++r) {
                int m = rb + i * 16 + r;
                *(ushort*)(smem + m * 512 + ((2 * h) ^ ((m & 7) << 4))) = f2b(acc[i][jj][r]);
            }
        }
    __syncthreads();
    // phase 2: t2 = t1 @ WcT^T, K=256
    f32x4 acc2[4][4] = {};
    #pragma unroll
    for (int k2 = 0; k2 < 4; ++k2) {
        #pragma unroll
        for (int ks = 0; ks < 2; ++ks) {
            const int cbyte = k2 * 128 + ks * 64 + kq;
            bf16x8 av[4], bv[4];
            #pragma unroll
            for (int i = 0; i < 4; ++i) {
                int m = wr + i * 16 + rr;
                av[i] = *(const bf16x8*)(smem + m * 512 + (cbyte ^ ((m & 7) << 4)));
                int h = wc + i * 16 + rr;
                bv[i] = *(const bf16x8*)((const char*)WcT + h * 512 + cbyte);
            }
            #pragma unroll
            for (int i = 0; i < 4; ++i)
                #pragma unroll
                for (int jj = 0; jj < 4; ++jj)
                    acc2[i][jj] = __builtin_amdgcn_mfma_f32_16x16x32_bf16(av[i], bv[jj], acc2[i][jj], 0, 0, 0);
        }
    }
    __syncthreads();
    // epilogue 2: tT[256 h][128 m] bf16, byte = h*256 + ((2m) ^ ((h&7)<<4))
    #pragma unroll
    for (int i = 0; i < 4; ++i)
        #pragma unroll
        for (int jj = 0; jj < 4; ++jj) {
            int h = cbh + jj * 16;
            int m = rb + i * 16;
            unsigned u0 = f2b(acc2[i][jj][0]) | ((unsigned)f2b(acc2[i][jj][1]) << 16);
            unsigned u1 = f2b(acc2[i][jj][2]) | ((unsigned)f2b(acc2[i][jj][3]) << 16);
            *(uint2*)(smem + h * 256 + ((2 * m) ^ ((h & 7) << 4))) = make_uint2(u0, u1);
        }
    __syncthreads();
    ushort* ob = t2T + (size_t)b * 256 * 1024 + m0;
    const int h = tid >> 1, mh = (tid & 1) * 64;
    #pragma unroll
    for (int i = 0; i < 8; ++i) {
        uint4 v = *(const uint4*)(smem + h * 256 + (((mh + i * 8) * 2) ^ ((h & 7) << 4)));
        *(uint4*)(ob + (size_t)h * 1024 + mh + i * 8) = v;
    }
}

// ---- k_O: out = relu((E_b @ t2T_b^T)/Z[m] + resv), fp32 out.  1-D grid 512, swizzled.
__global__ __launch_bounds__(256) void k_O(const ushort* __restrict__ E, const ushort* __restrict__ t2T,
                                           const ushort* __restrict__ resv, const float* __restrict__ Z,
                                           float* __restrict__ out) {
    GEMM_LDS
    f32x4 acc[4][4] = {};
    const int j = (blockIdx.x & 7) * 64 + (blockIdx.x >> 3);
    const int n0 = (j & 1) * 128, m0 = ((j >> 1) & 7) * 128, b = j >> 4;
    gemm_core(E + ((size_t)b << 20) + (size_t)m0 * 1024,
              t2T + (size_t)b * 256 * 1024 + (size_t)n0 * 1024, 1024, As0, Bs0, As1, Bs1, acc);
    EPI_COORDS
    #pragma unroll
    for (int i = 0; i < 4; ++i)
        #pragma unroll
        for (int jj = 0; jj < 4; ++jj)
            #pragma unroll
            for (int r = 0; r < 4; ++r) {
                int row = m0 + rb + i * 16 + r;
                float iz = 1.0f / Z[b * 1024 + row];
                size_t off = ((size_t)(b * 1024 + row)) * 256 + n0 + cb + jj * 16;
                out[off] = fmaxf(acc[i][jj][r] * iz + b2f(resv[off]), 0.0f);
            }
}

extern "C" void kernel_launch(void* const* d_in, const int* in_sizes, int n_in,
                              void* d_out, int out_size, void* d_ws, size_t ws_size,
                              hipStream_t stream) {
    const float* V     = (const float*)d_in[0];
    const float* alpha = (const float*)d_in[1];
    const float* WVw   = (const float*)d_in[2];
    const float* WVb   = (const float*)d_in[3];
    const float* Wc    = (const float*)d_in[4];
    const float* resw  = (const float*)d_in[5];
    const float* resb  = (const float*)d_in[6];
    float* out = (float*)d_out;

    char* W = (char*)d_ws;
    ushort* Vb   = (ushort*)(W);                         // 48 MB
    ushort* E    = (ushort*)(W + (48ull  << 20));        // 64 MB
    ushort* Vp   = (ushort*)(W + (112ull << 20));        // 16 MB
    ushort* resv = (ushort*)(W + (128ull << 20));        // 16 MB
    ushort* VpZT = (ushort*)(W + (144ull << 20));        // 16 MB
    ushort* t2T  = (ushort*)(W + (192ull << 20));        // 16 MB
    ushort* Wcat = (ushort*)(W + (208ull << 20));        // 768 KB
    ushort* WcT  = (ushort*)(W + (209ull << 20));        // 128 KB
    float*  gpart= (float*) (W + (210ull << 20));        // 1.5 MB (16 chunks)
    float*  g    = (float*) (W + (212ull << 20));        // 96 KB
    float*  gW   = (float*) (W + (212ull << 20) + (128u << 10)); // 32 KB
    float*  shv  = (float*) (W + (212ull << 20) + (256u << 10)); // 128 B
    float*  rn   = (float*) (W + (212ull << 20) + (512u << 10)); // 128 KB
    float*  Z    = (float*) (W + (213ull << 20));        // 128 KB

    hipMemsetAsync(Z, 0, 32768 * sizeof(float), stream);

    k_castmean<<<dim3(32, 16), 192, 0, stream>>>(V, Vb, gpart);
    k_gsum<<<96, 256, 0, stream>>>(gpart, g);
    k_gW<<<32, 256, 0, stream>>>(g, WVw, gW);
    k_castw<<<192, 256, 0, stream>>>(WVw, resw, Wcat);
    k_wct<<<dim3(4, 4), 256, 0, stream>>>(Wc, WcT);
    k_proj<<<1024, 256, 0, stream>>>(Vb, Wcat, WVb, resb, gW, alpha, Vp, resv);
    k_rownorm<<<8192, 256, 0, stream>>>(Vp, rn);
    k_shift<<<32, 256, 0, stream>>>(rn, shv);
    k_sim<<<2048, 256, 0, stream>>>(Vp, shv, E, Z);
    k_trbs<<<dim3(4, 16, 32), 256, 0, stream>>>(Vp, Z, VpZT);
    k_t12<<<256, 512, 0, stream>>>(E, VpZT, WcT, t2T);
    k_O<<<512, 256, 0, stream>>>(E, t2T, resv, Z, out);
}

// Round 10
// 381.444 us; speedup vs baseline: 1.0348x; 1.0348x over previous
//
#include <hip/hip_runtime.h>
#include <math.h>

// B=32, M=1024, D=768, H=256.
// Vb = bf16(V); g = mean_m V (fused with cast); gW = g@WVw^T (fp32)
// [Vp | resv] = Vb @ [WVw;resw]^T (+epilogues), bf16      -- MFMA core (single-buf), XCD-swizzled
// rn[m] = ||Vp_m||^2 ; shift[b] = max_m rn
// E = exp(Vp@Vp^T - shift[b]) bf16: SYMMETRIC -> only ti<=tj tiles computed,
//     mirror via LDS transpose; Z[m] += row-sums AND col-sums (fused atomics)
// k_t12 (fused): t1 = E @ (Vp/Z) -> LDS; t2 = t1 @ Wc; writes t2T directly
// out = relu((E @ t2T^T)/Z[m] + resv)  fp32               -- MFMA core

typedef __attribute__((ext_vector_type(8))) short bf16x8;
typedef __attribute__((ext_vector_type(4))) float f32x4;

__device__ __forceinline__ ushort f2b(float f) {
    unsigned u = __float_as_uint(f);
    return (ushort)((u + 0x7fffu + ((u >> 16) & 1u)) >> 16);
}
__device__ __forceinline__ float b2f(ushort u) {
    return __uint_as_float((unsigned)u << 16);
}
__device__ __forceinline__ uint4 pack8(float4 a, float4 b) {
    uint4 r;
    r.x = f2b(a.x) | ((unsigned)f2b(a.y) << 16);
    r.y = f2b(a.z) | ((unsigned)f2b(a.w) << 16);
    r.z = f2b(b.x) | ((unsigned)f2b(b.y) << 16);
    r.w = f2b(b.z) | ((unsigned)f2b(b.w) << 16);
    return r;
}

__device__ __forceinline__ void gl16(const void* g, void* l) {
    __builtin_amdgcn_global_load_lds(
        (__attribute__((address_space(1))) const unsigned*)g,
        (__attribute__((address_space(3))) unsigned*)l, 16, 0, 0);
}

// ---- m97-style 128x128 GEMM core, BK=64, global_load_lds(16B), XOR-swizzled LDS.
// Single-buffered (measured best vs dbuf: 385 vs 395 us; occupancy > pipelining here).
__device__ __forceinline__ void gemm_core(const ushort* __restrict__ A,
                                          const ushort* __restrict__ Bt,
                                          int K, ushort* As, ushort* Bs,
                                          f32x4 acc[4][4]) {
    const int tid = threadIdx.x;
    const int lane = tid & 63;
    const int wave = tid >> 6;
    const int l8 = lane >> 3, l7 = lane & 7;
    const int swz = ((l7 ^ l8) << 4);
    const char* pa[4];
    const char* pb[4];
    ushort* la[4];
    ushort* lb[4];
    #pragma unroll
    for (int i = 0; i < 4; ++i) {
        int r = (wave * 4 + i) * 8 + l8;
        pa[i] = (const char*)A + (size_t)r * (K * 2) + swz;
        pb[i] = (const char*)Bt + (size_t)r * (K * 2) + swz;
        la[i] = As + (wave * 4 + i) * 512;
        lb[i] = Bs + (wave * 4 + i) * 512;
    }
    const int rr = lane & 15;
    const int kq = (lane >> 4) << 4;
    const int mask = (rr & 7) << 4;
    const int c0 = kq ^ mask;
    const int c1 = (64 + kq) ^ mask;
    const int wr = (wave >> 1) * 64, wc = (wave & 1) * 64;
    const int arow0 = (wr + rr) * 128, brow0 = (wc + rr) * 128;

    for (int k0 = 0; k0 < K; k0 += 64) {
        __syncthreads();
        #pragma unroll
        for (int i = 0; i < 4; ++i) {
            gl16(pa[i], la[i]);
            gl16(pb[i], lb[i]);
            pa[i] += 128; pb[i] += 128;
        }
        __syncthreads();
        #pragma unroll
        for (int ks = 0; ks < 2; ++ks) {
            const int cc = ks ? c1 : c0;
            bf16x8 av[4], bv[4];
            #pragma unroll
            for (int i = 0; i < 4; ++i) {
                av[i] = *(const bf16x8*)((const char*)As + arow0 + i * 2048 + cc);
                bv[i] = *(const bf16x8*)((const char*)Bs + brow0 + i * 2048 + cc);
            }
            #pragma unroll
            for (int i = 0; i < 4; ++i)
                #pragma unroll
                for (int j = 0; j < 4; ++j)
                    acc[i][j] = __builtin_amdgcn_mfma_f32_16x16x32_bf16(av[i], bv[j], acc[i][j], 0, 0, 0);
        }
    }
}

#define EPI_COORDS \
    const int lane = threadIdx.x & 63; \
    const int wave = threadIdx.x >> 6; \
    const int rb = (wave >> 1) * 64 + (lane >> 4) * 4; \
    const int cb = (wave & 1) * 64 + (lane & 15);

// ---- cast V->bf16 fused with column partial sums for the mean
__global__ __launch_bounds__(192) void k_castmean(const float* __restrict__ V,
                                                  ushort* __restrict__ Vb,
                                                  float* __restrict__ gpart) {
    const int b = blockIdx.x, mc = blockIdx.y, t = threadIdx.x;
    const size_t base = ((size_t)(b * 1024 + mc * 64)) * 768 + t * 4;
    const float* src = V + base;
    ushort* dst = Vb + base;
    float4 s = make_float4(0.f, 0.f, 0.f, 0.f);
    for (int r = 0; r < 64; ++r) {
        float4 v = *(const float4*)(src + (size_t)r * 768);
        s.x += v.x; s.y += v.y; s.z += v.z; s.w += v.w;
        unsigned u0 = f2b(v.x) | ((unsigned)f2b(v.y) << 16);
        unsigned u1 = f2b(v.z) | ((unsigned)f2b(v.w) << 16);
        *(uint2*)(dst + (size_t)r * 768) = make_uint2(u0, u1);
    }
    *(float4*)&gpart[(size_t)(mc * 32 + b) * 768 + t * 4] = s;
}

__global__ __launch_bounds__(256) void k_gsum(const float* __restrict__ gpart, float* __restrict__ g) {
    int idx = blockIdx.x * 256 + threadIdx.x;       // < 24576
    float s = 0.f;
    #pragma unroll
    for (int c = 0; c < 16; ++c) s += gpart[(size_t)c * 24576 + idx];
    g[idx] = s * (1.0f / 1024.0f);
}

__global__ __launch_bounds__(256) void k_gW(const float* __restrict__ g,
                                            const float* __restrict__ WVw,
                                            float* __restrict__ gW) {
    int idx = blockIdx.x * 256 + threadIdx.x;       // < 8192
    int b = idx >> 8, h = idx & 255;
    const float* gr = g + b * 768;
    const float* wr = WVw + (size_t)h * 768;
    float s = 0.f;
    for (int d = 0; d < 768; ++d) s += gr[d] * wr[d];
    gW[idx] = s;
}

__global__ __launch_bounds__(256) void k_castw(const float* __restrict__ WVw,
                                               const float* __restrict__ resw,
                                               ushort* __restrict__ Wcat) {
    int id = blockIdx.x * 256 + threadIdx.x;        // < 49152
    int n = id / 96, c = (id - n * 96) * 8;
    const float* src = (n < 256) ? (WVw + (size_t)n * 768 + c) : (resw + (size_t)(n - 256) * 768 + c);
    *(uint4*)(Wcat + (size_t)n * 768 + c) = pack8(*(const float4*)src, *(const float4*)(src + 4));
}

// ---- WcT[k][h] = bf16(Wc[h][k]), 256x256
__global__ __launch_bounds__(256) void k_wct(const float* __restrict__ Wc, ushort* __restrict__ WcT) {
    __shared__ float t[64][65];
    const int r0 = blockIdx.y * 64, c0 = blockIdx.x * 64;
    const int tid = threadIdx.x;
    #pragma unroll
    for (int i = 0; i < 4; ++i) {
        int r = (tid >> 4) + i * 16, c4 = (tid & 15) * 4;
        float4 v = *(const float4*)&Wc[(size_t)(r0 + r) * 256 + c0 + c4];
        t[r][c4] = v.x; t[r][c4 + 1] = v.y; t[r][c4 + 2] = v.z; t[r][c4 + 3] = v.w;
    }
    __syncthreads();
    #pragma unroll
    for (int i = 0; i < 4; ++i) {
        int oc = (tid >> 4) + i * 16, r4 = (tid & 15) * 4;
        unsigned lo = f2b(t[r4][oc]) | ((unsigned)f2b(t[r4 + 1][oc]) << 16);
        unsigned hi = f2b(t[r4 + 2][oc]) | ((unsigned)f2b(t[r4 + 3][oc]) << 16);
        *(uint2*)&WcT[(size_t)(c0 + oc) * 256 + r0 + r4] = make_uint2(lo, hi);
    }
}

// ---- k_proj: [32768 x 512] = Vb @ Wcat^T.  1-D grid 1024, XCD-swizzled.
__global__ __launch_bounds__(256) void k_proj(const ushort* __restrict__ Vb, const ushort* __restrict__ Wcat,
                                              const float* __restrict__ WVb, const float* __restrict__ resb,
                                              const float* __restrict__ gW, const float* __restrict__ alpha_p,
                                              ushort* __restrict__ Vp, ushort* __restrict__ resv) {
    __shared__ ushort As[128 * 64], Bs[128 * 64];
    f32x4 acc[4][4] = {};
    const int j = (blockIdx.x & 7) * 128 + (blockIdx.x >> 3);  // bijective, nwg%8==0
    const int n0 = (j & 3) * 128, m0 = (j >> 2) * 128;
    gemm_core(Vb + (size_t)m0 * 768, Wcat + (size_t)n0 * 768, 768, As, Bs, acc);
    EPI_COORDS
    const float alpha = *alpha_p, oma = 1.0f - alpha;
    #pragma unroll
    for (int i = 0; i < 4; ++i)
        #pragma unroll
        for (int jj = 0; jj < 4; ++jj) {
            int gcol = n0 + cb + jj * 16;
            #pragma unroll
            for (int r = 0; r < 4; ++r) {
                int grow = m0 + rb + i * 16 + r;
                float v = acc[i][jj][r];
                if (gcol < 256) {
                    float o = alpha * v + oma * gW[((grow >> 10) << 8) + gcol] + WVb[gcol];
                    Vp[(size_t)grow * 256 + gcol] = f2b(o);
                } else {
                    resv[(size_t)grow * 256 + gcol - 256] = f2b(v + resb[gcol - 256]);
                }
            }
        }
}

// ---- k_rownorm: rn[row] = ||Vp_row||^2
__global__ __launch_bounds__(256) void k_rownorm(const ushort* __restrict__ Vp, float* __restrict__ rn) {
    const int row = blockIdx.x * 4 + (threadIdx.x >> 6);
    const int lane = threadIdx.x & 63;
    uint2 v = *(const uint2*)(Vp + (size_t)row * 256 + lane * 4);
    float f0 = b2f((ushort)(v.x & 0xffff)), f1 = b2f((ushort)(v.x >> 16));
    float f2 = b2f((ushort)(v.y & 0xffff)), f3 = b2f((ushort)(v.y >> 16));
    float s = f0 * f0 + f1 * f1 + f2 * f2 + f3 * f3;
    #pragma unroll
    for (int o = 32; o > 0; o >>= 1) s += __shfl_xor(s, o, 64);
    if (lane == 0) rn[row] = s;
}

__global__ __launch_bounds__(256) void k_shift(const float* __restrict__ rn, float* __restrict__ shift) {
    const int b = blockIdx.x, tid = threadIdx.x;
    const float* p = rn + b * 1024;
    float m = fmaxf(fmaxf(p[tid], p[tid + 256]), fmaxf(p[tid + 512], p[tid + 768]));
    #pragma unroll
    for (int o = 32; o > 0; o >>= 1) m = fmaxf(m, __shfl_xor(m, o, 64));
    __shared__ float red[4];
    if ((tid & 63) == 0) red[tid >> 6] = m;
    __syncthreads();
    if (tid == 0)
        shift[b] = fmaxf(fmaxf(red[0], red[1]), fmaxf(red[2], red[3]));
}

// ---- k_sim (symmetric): only tiles ti<=tj.  E-tile = exp(Vp[m-panel]@Vp[n-panel]^T - sh).
// Off-diagonal: mirror E[n,m]=E[m,n] via LDS transpose (bit-exact; same fp32 sums),
// Z gets row-sum atomics (n-blocks >= tm) and mirrored col-sum atomics (n-blocks < tm).
// Grid 1152 = 36 tiles x 32 batches, XCD-swizzled (batch-per-XCD L2 locality).
__global__ __launch_bounds__(256) void k_sim(const ushort* __restrict__ Vp,
                                             const float* __restrict__ shift,
                                             ushort* __restrict__ E,
                                             float* __restrict__ Z) {
    __shared__ ushort smem[16384];   // gemm: As=smem, Bs=smem+8192; epilogue: 128x128 bf16 tile
    f32x4 acc[4][4] = {};
    const int jlin = (blockIdx.x & 7) * 144 + (blockIdx.x >> 3);   // bijective, 1152%8==0
    const int b = jlin / 36;
    int idx = jlin - b * 36;
    int ti = 0;
    while (idx >= 8 - ti) { idx -= 8 - ti; ++ti; }
    const int tj = ti + idx;
    const int m0 = ti * 128, n0 = tj * 128;
    const ushort* Vb_ = Vp + (size_t)b * 1024 * 256;
    gemm_core(Vb_ + (size_t)m0 * 256, Vb_ + (size_t)n0 * 256, 256, smem, smem + 8192, acc);
    ushort* Eb = E + ((size_t)b << 20);
    const float sh = shift[b];
    EPI_COORDS
    // exp in place; direct write + row-sum atomics
    #pragma unroll
    for (int i = 0; i < 4; ++i)
        #pragma unroll
        for (int r = 0; r < 4; ++r) {
            const int row = m0 + rb + i * 16 + r;
            float s = 0.f;
            #pragma unroll
            for (int jj = 0; jj < 4; ++jj) {
                float e = __expf(acc[i][jj][r] - sh);
                acc[i][jj][r] = e;
                s += e;
                Eb[(size_t)row * 1024 + n0 + cb + jj * 16] = f2b(e);
            }
            s += __shfl_xor(s, 1, 64);
            s += __shfl_xor(s, 2, 64);
            s += __shfl_xor(s, 4, 64);
            s += __shfl_xor(s, 8, 64);
            if ((lane & 15) == 0)
                atomicAdd(&Z[b * 1024 + row], s);
        }
    if (ti != tj) {
        __syncthreads();   // all waves done with gemm LDS reads
        // store tile transposed-layout: [col][ (2*row) ^ ((col&7)<<4) ]  (16B-block XOR)
        #pragma unroll
        for (int i = 0; i < 4; ++i)
            #pragma unroll
            for (int jj = 0; jj < 4; ++jj) {
                const int col = cb + jj * 16;
                unsigned u0 = f2b(acc[i][jj][0]) | ((unsigned)f2b(acc[i][jj][1]) << 16);
                unsigned u1 = f2b(acc[i][jj][2]) | ((unsigned)f2b(acc[i][jj][3]) << 16);
                *(uint2*)((char*)smem + col * 256 + ((2 * (rb + i * 16)) ^ ((col & 7) << 4))) =
                    make_uint2(u0, u1);
            }
        // mirrored col-sum atomics into Z[n0+col]
        #pragma unroll
        for (int jj = 0; jj < 4; ++jj) {
            float cs = 0.f;
            #pragma unroll
            for (int i = 0; i < 4; ++i)
                #pragma unroll
                for (int r = 0; r < 4; ++r) cs += acc[i][jj][r];
            cs += __shfl_xor(cs, 16, 64);
            cs += __shfl_xor(cs, 32, 64);
            if (lane < 16)
                atomicAdd(&Z[b * 1024 + n0 + cb + jj * 16], cs);
        }
        __syncthreads();
        // mirror write: E[n0+c][m0 + 0..127], coalesced uint4
        const int tid = threadIdx.x;
        const int c = tid >> 1, half = tid & 1;
        ushort* orow = Eb + (size_t)(n0 + c) * 1024 + m0 + half * 64;
        #pragma unroll
        for (int k = 0; k < 8; ++k) {
            uint4 v = *(const uint4*)((const char*)smem + c * 256 +
                                      (((half * 64 + k * 8) * 2) ^ ((c & 7) << 4)));
            *(uint4*)(orow + k * 8) = v;
        }
    }
}

// ---- k_trbs: VpZT[b][h][n] = Vp[b][n][h] / Z[b*1024+n]
__global__ __launch_bounds__(256) void k_trbs(const ushort* __restrict__ Vp,
                                              const float* __restrict__ Z,
                                              ushort* __restrict__ VpZT) {
    __shared__ ushort t[64][68];
    const int b = blockIdx.z;
    const ushort* ib = Vp + (size_t)b * 1024 * 256;
    ushort* ob = VpZT + (size_t)b * 256 * 1024;
    const int c0 = blockIdx.x * 64, r0 = blockIdx.y * 64;
    const int tid = threadIdx.x;
    #pragma unroll
    for (int i = 0; i < 4; ++i) {
        int r = (tid >> 4) + i * 16, c4 = (tid & 15) * 4;
        uint2 v = *(const uint2*)(ib + (size_t)(r0 + r) * 256 + c0 + c4);
        float iz = 1.0f / Z[b * 1024 + r0 + r];
        unsigned lo = f2b(b2f((ushort)(v.x & 0xffff)) * iz) |
                      ((unsigned)f2b(b2f((ushort)(v.x >> 16)) * iz) << 16);
        unsigned hi = f2b(b2f((ushort)(v.y & 0xffff)) * iz) |
                      ((unsigned)f2b(b2f((ushort)(v.y >> 16)) * iz) << 16);
        *(uint2*)&t[r][c4] = make_uint2(lo, hi);
    }
    __syncthreads();
    #pragma unroll
    for (int i = 0; i < 4; ++i) {
        int oc = (tid >> 4) + i * 16, r4 = (tid & 15) * 4;
        unsigned lo = t[r4][oc] | ((unsigned)t[r4 + 1][oc] << 16);
        unsigned hi = t[r4 + 2][oc] | ((unsigned)t[r4 + 3][oc] << 16);
        *(uint2*)(ob + (size_t)(c0 + oc) * 1024 + r0 + r4) = make_uint2(lo, hi);
    }
}

// ---- k_t12 (fused): per block: 128 rows m x full 256 cols.
// Phase 1: t1 = E[m-panel] @ VpZT^T (K=1024) -> LDS (XOR-swizzled 128x256 bf16)
// Phase 2: t2 = t1 @ WcT^T (K=256), B-frags direct from L2
// Epilogue: transpose via LDS, write t2T[b][h][m] coalesced.
// 512 threads = 8 waves (2 row x 4 col quadrants).  Grid 256, XCD-swizzled.
__global__ __launch_bounds__(512) void k_t12(const ushort* __restrict__ E,
                                             const ushort* __restrict__ VpZT,
                                             const ushort* __restrict__ WcT,
                                             ushort* __restrict__ t2T) {
    __shared__ char smem[65536];
    char* Asb = smem;            // 16 KB: 128 rows x 128 B  (phase 1)
    char* Bsb = smem + 16384;    // 32 KB: 256 rows x 128 B  (phase 1)
    // whole smem = t1buf [128 m][512 B] (phase 2 A), then tT [256 h][256 B]

    const int j = (blockIdx.x & 7) * 32 + (blockIdx.x >> 3);
    const int m0 = (j & 7) * 128;
    const int b = j >> 3;
    const ushort* Eb = E + ((size_t)b << 20) + (size_t)m0 * 1024;
    const ushort* Vz = VpZT + (size_t)b * 256 * 1024;
    const int tid = threadIdx.x;
    const int lane = tid & 63, wave = tid >> 6;
    const int l8 = lane >> 3, l7 = lane & 7;
    const int swz = (l7 ^ l8) << 4;

    const char* pa[2]; char* la[2];
    const char* pb[4]; char* lb[4];
    #pragma unroll
    for (int ii = 0; ii < 2; ++ii) {
        int r = wave * 16 + ii * 8 + l8;
        pa[ii] = (const char*)(Eb + (size_t)r * 1024) + swz;
        la[ii] = Asb + (wave * 16 + ii * 8) * 128;
    }
    #pragma unroll
    for (int ii = 0; ii < 4; ++ii) {
        int r = wave * 32 + ii * 8 + l8;
        pb[ii] = (const char*)(Vz + (size_t)r * 1024) + swz;
        lb[ii] = Bsb + (wave * 32 + ii * 8) * 128;
    }
    const int rr = lane & 15;
    const int kq = (lane >> 4) << 4;
    const int mask = (rr & 7) << 4;
    const int wr = (wave >> 2) * 64, wc = (wave & 3) * 64;
    f32x4 acc[4][4] = {};
    for (int k0 = 0; k0 < 1024; k0 += 64) {
        __syncthreads();
        #pragma unroll
        for (int ii = 0; ii < 2; ++ii) { gl16(pa[ii], la[ii]); pa[ii] += 128; }
        #pragma unroll
        for (int ii = 0; ii < 4; ++ii) { gl16(pb[ii], lb[ii]); pb[ii] += 128; }
        __syncthreads();
        #pragma unroll
        for (int ks = 0; ks < 2; ++ks) {
            const int cc = (ks * 64 + kq) ^ mask;
            bf16x8 av[4], bv[4];
            #pragma unroll
            for (int i = 0; i < 4; ++i) {
                av[i] = *(const bf16x8*)(Asb + (wr + i * 16 + rr) * 128 + cc);
                bv[i] = *(const bf16x8*)(Bsb + (wc + i * 16 + rr) * 128 + cc);
            }
            #pragma unroll
            for (int i = 0; i < 4; ++i)
                #pragma unroll
                for (int jj = 0; jj < 4; ++jj)
                    acc[i][jj] = __builtin_amdgcn_mfma_f32_16x16x32_bf16(av[i], bv[jj], acc[i][jj], 0, 0, 0);
        }
    }
    // epilogue 1: t1 -> smem [128 m][256 h] bf16, byte = m*512 + ((2h) ^ ((m&7)<<4))
    __syncthreads();
    const int rb = wr + (lane >> 4) * 4;
    const int cbh = wc + (lane & 15);
    #pragma unroll
    for (int i = 0; i < 4; ++i)
        #pragma unroll
        for (int jj = 0; jj < 4; ++jj) {
            int h = cbh + jj * 16;
            #pragma unroll
            for (int r = 0; r < 4; ++r) {
                int m = rb + i * 16 + r;
                *(ushort*)(smem + m * 512 + ((2 * h) ^ ((m & 7) << 4))) = f2b(acc[i][jj][r]);
            }
        }
    __syncthreads();
    // phase 2: t2 = t1 @ WcT^T, K=256
    f32x4 acc2[4][4] = {};
    #pragma unroll
    for (int k2 = 0; k2 < 4; ++k2) {
        #pragma unroll
        for (int ks = 0; ks < 2; ++ks) {
            const int cbyte = k2 * 128 + ks * 64 + kq;
            bf16x8 av[4], bv[4];
            #pragma unroll
            for (int i = 0; i < 4; ++i) {
                int m = wr + i * 16 + rr;
                av[i] = *(const bf16x8*)(smem + m * 512 + (cbyte ^ ((m & 7) << 4)));
                int h = wc + i * 16 + rr;
                bv[i] = *(const bf16x8*)((const char*)WcT + h * 512 + cbyte);
            }
            #pragma unroll
            for (int i = 0; i < 4; ++i)
                #pragma unroll
                for (int jj = 0; jj < 4; ++jj)
                    acc2[i][jj] = __builtin_amdgcn_mfma_f32_16x16x32_bf16(av[i], bv[jj], acc2[i][jj], 0, 0, 0);
        }
    }
    __syncthreads();
    // epilogue 2: tT[256 h][128 m] bf16, byte = h*256 + ((2m) ^ ((h&7)<<4))
    #pragma unroll
    for (int i = 0; i < 4; ++i)
        #pragma unroll
        for (int jj = 0; jj < 4; ++jj) {
            int h = cbh + jj * 16;
            int m = rb + i * 16;
            unsigned u0 = f2b(acc2[i][jj][0]) | ((unsigned)f2b(acc2[i][jj][1]) << 16);
            unsigned u1 = f2b(acc2[i][jj][2]) | ((unsigned)f2b(acc2[i][jj][3]) << 16);
            *(uint2*)(smem + h * 256 + ((2 * m) ^ ((h & 7) << 4))) = make_uint2(u0, u1);
        }
    __syncthreads();
    ushort* ob = t2T + (size_t)b * 256 * 1024 + m0;
    const int h = tid >> 1, mh = (tid & 1) * 64;
    #pragma unroll
    for (int i = 0; i < 8; ++i) {
        uint4 v = *(const uint4*)(smem + h * 256 + (((mh + i * 8) * 2) ^ ((h & 7) << 4)));
        *(uint4*)(ob + (size_t)h * 1024 + mh + i * 8) = v;
    }
}

// ---- k_O: out = relu((E_b @ t2T_b^T)/Z[m] + resv), fp32 out.  1-D grid 512, swizzled.
__global__ __launch_bounds__(256) void k_O(const ushort* __restrict__ E, const ushort* __restrict__ t2T,
                                           const ushort* __restrict__ resv, const float* __restrict__ Z,
                                           float* __restrict__ out) {
    __shared__ ushort As[128 * 64], Bs[128 * 64];
    f32x4 acc[4][4] = {};
    const int j = (blockIdx.x & 7) * 64 + (blockIdx.x >> 3);
    const int n0 = (j & 1) * 128, m0 = ((j >> 1) & 7) * 128, b = j >> 4;
    gemm_core(E + ((size_t)b << 20) + (size_t)m0 * 1024,
              t2T + (size_t)b * 256 * 1024 + (size_t)n0 * 1024, 1024, As, Bs, acc);
    EPI_COORDS
    #pragma unroll
    for (int i = 0; i < 4; ++i)
        #pragma unroll
        for (int jj = 0; jj < 4; ++jj)
            #pragma unroll
            for (int r = 0; r < 4; ++r) {
                int row = m0 + rb + i * 16 + r;
                float iz = 1.0f / Z[b * 1024 + row];
                size_t off = ((size_t)(b * 1024 + row)) * 256 + n0 + cb + jj * 16;
                out[off] = fmaxf(acc[i][jj][r] * iz + b2f(resv[off]), 0.0f);
            }
}

extern "C" void kernel_launch(void* const* d_in, const int* in_sizes, int n_in,
                              void* d_out, int out_size, void* d_ws, size_t ws_size,
                              hipStream_t stream) {
    const float* V     = (const float*)d_in[0];
    const float* alpha = (const float*)d_in[1];
    const float* WVw   = (const float*)d_in[2];
    const float* WVb   = (const float*)d_in[3];
    const float* Wc    = (const float*)d_in[4];
    const float* resw  = (const float*)d_in[5];
    const float* resb  = (const float*)d_in[6];
    float* out = (float*)d_out;

    char* W = (char*)d_ws;
    ushort* Vb   = (ushort*)(W);                         // 48 MB
    ushort* E    = (ushort*)(W + (48ull  << 20));        // 64 MB
    ushort* Vp   = (ushort*)(W + (112ull << 20));        // 16 MB
    ushort* resv = (ushort*)(W + (128ull << 20));        // 16 MB
    ushort* VpZT = (ushort*)(W + (144ull << 20));        // 16 MB
    ushort* t2T  = (ushort*)(W + (192ull << 20));        // 16 MB
    ushort* Wcat = (ushort*)(W + (208ull << 20));        // 768 KB
    ushort* WcT  = (ushort*)(W + (209ull << 20));        // 128 KB
    float*  gpart= (float*) (W + (210ull << 20));        // 1.5 MB (16 chunks)
    float*  g    = (float*) (W + (212ull << 20));        // 96 KB
    float*  gW   = (float*) (W + (212ull << 20) + (128u << 10)); // 32 KB
    float*  shv  = (float*) (W + (212ull << 20) + (256u << 10)); // 128 B
    float*  rn   = (float*) (W + (212ull << 20) + (512u << 10)); // 128 KB
    float*  Z    = (float*) (W + (213ull << 20));        // 128 KB

    hipMemsetAsync(Z, 0, 32768 * sizeof(float), stream);

    k_castmean<<<dim3(32, 16), 192, 0, stream>>>(V, Vb, gpart);
    k_gsum<<<96, 256, 0, stream>>>(gpart, g);
    k_gW<<<32, 256, 0, stream>>>(g, WVw, gW);
    k_castw<<<192, 256, 0, stream>>>(WVw, resw, Wcat);
    k_wct<<<dim3(4, 4), 256, 0, stream>>>(Wc, WcT);
    k_proj<<<1024, 256, 0, stream>>>(Vb, Wcat, WVb, resb, gW, alpha, Vp, resv);
    k_rownorm<<<8192, 256, 0, stream>>>(Vp, rn);
    k_shift<<<32, 256, 0, stream>>>(rn, shv);
    k_sim<<<1152, 256, 0, stream>>>(Vp, shv, E, Z);
    k_trbs<<<dim3(4, 16, 32), 256, 0, stream>>>(Vp, Z, VpZT);
    k_t12<<<256, 512, 0, stream>>>(E, VpZT, WcT, t2T);
    k_O<<<512, 256, 0, stream>>>(E, t2T, resv, Z, out);
}